// Round 10
// baseline (215.884 us; speedup 1.0000x reference)
//
#include <hip/hip_runtime.h>
#include <hip/hip_bf16.h>
#include <hip/hip_cooperative_groups.h>
namespace cg = cooperative_groups;

#define NL 2048   // languages
#define DE 64     // embedding dim
#define VV 2048   // vocab
#define BT 64     // pair tile (64x64)
#define NT (NL / BT)              // 32 tiles per side
#define NBLK (NT * (NT + 1) / 2)  // 528 triangular tiles
#define STT 68    // [dim][idx] stride: reads/writes <=2-way bank aliasing (free)

// ws layout (no memset needed — every word written before read):
// [0:2112)      float pmax[528]
// [4096:6208)   float psum[528]
// [8192:10304)  uint  pcnt[528]
// [12288:20480) int   perm[2048]
// [20480:28672) int   sids[2048]

union SharedU {
    struct {
        float Eit[DE][STT];
        float Ejt[DE][STT];
        int   idi[BT];
        int   idj[BT];
        float wm[4];
        float    wsum_l[4];
        unsigned wcnt_l[4];
    } loss;
    struct {
        unsigned hist[VV];
        unsigned offs[VV];
        unsigned wtot[4];
        unsigned wexc[4];
    } sort;
    struct {
        float wl[4];
    } mx;
    struct {
        double   sl[4];
        unsigned cl[4];
    } fin;
};

__global__ __launch_bounds__(256) void fused_kernel(
    const int* __restrict__ ids, const float* __restrict__ emb,
    const float* __restrict__ tree, const float* __restrict__ mapd,
    float* __restrict__ pmax, int* __restrict__ perm, int* __restrict__ sids,
    float* __restrict__ psum, unsigned* __restrict__ pcnt,
    float* __restrict__ out)
{
    __shared__ SharedU sh;
    cg::grid_group grid = cg::this_grid();

    const int t = threadIdx.x;
    const int lane = t & 63, wave = t >> 6;
    const int L = blockIdx.x;

    // ================= Phase 0: max (blocks 0..526) / sort (block 527) ==========
    if (L < NBLK - 1) {
        const float4* m4 = (const float4*)mapd;
        const int n4 = (VV * VV) / 4;
        float v = 0.0f;  // map_dist >= 0
        for (int i = L * 256 + t; i < n4; i += (NBLK - 1) * 256) {
            float4 x = m4[i];
            v = fmaxf(v, fmaxf(fmaxf(x.x, x.y), fmaxf(x.z, x.w)));
        }
        #pragma unroll
        for (int o = 32; o > 0; o >>= 1)
            v = fmaxf(v, __shfl_down(v, o));
        if (lane == 0) sh.mx.wl[wave] = v;
        __syncthreads();
        if (t == 0) {
            float m = fmaxf(fmaxf(sh.mx.wl[0], sh.mx.wl[1]), fmaxf(sh.mx.wl[2], sh.mx.wl[3]));
            pmax[L] = m;   // plain store
        }
    } else {
        // 256-thread counting sort of 2048 ids (8 elements / thread)
        #pragma unroll
        for (int k = 0; k < 8; ++k) sh.sort.hist[t * 8 + k] = 0u;
        __syncthreads();
        int myid[8];
        #pragma unroll
        for (int k = 0; k < 8; ++k) {
            myid[k] = ids[t * 8 + k];
            atomicAdd(&sh.sort.hist[myid[k]], 1u);
        }
        __syncthreads();
        unsigned loc[8], s = 0;
        #pragma unroll
        for (int k = 0; k < 8; ++k) { loc[k] = sh.sort.hist[t * 8 + k]; s += loc[k]; }
        unsigned ps = s;
        #pragma unroll
        for (int o = 1; o < 64; o <<= 1) {
            unsigned u = __shfl_up(ps, o);
            if (lane >= o) ps += u;
        }
        if (lane == 63) sh.sort.wtot[wave] = ps;
        __syncthreads();
        if (wave == 0 && lane < 4) {
            unsigned v = sh.sort.wtot[lane];
            unsigned pv = v;
            #pragma unroll
            for (int o = 1; o < 4; o <<= 1) {
                unsigned u = __shfl_up(pv, o);
                if (lane >= o) pv += u;
            }
            sh.sort.wexc[lane] = pv - v;
        }
        __syncthreads();
        unsigned ex = sh.sort.wexc[wave] + ps - s;
        #pragma unroll
        for (int k = 0; k < 8; ++k) { sh.sort.offs[t * 8 + k] = ex; ex += loc[k]; }
        __syncthreads();
        #pragma unroll
        for (int k = 0; k < 8; ++k) {
            unsigned p = atomicAdd(&sh.sort.offs[myid[k]], 1u);
            perm[p] = t * 8 + k;
            sids[p] = myid[k];
        }
        if (t == 0) pmax[NBLK - 1] = 0.0f;  // neutral for max
    }

    grid.sync();

    // ================= Phase 1: global-max fold + tile loss ======================
    // Triangular decode (NT=32): L -> (bi, bj), bi <= bj
    int bi = (int)((65.0f - sqrtf(4225.0f - 8.0f * (float)L)) * 0.5f);
    if (bi > NT - 1) bi = NT - 1;
    if (bi < 0) bi = 0;
    while (NT * bi - bi * (bi - 1) / 2 > L) --bi;
    while (NT * (bi + 1) - (bi + 1) * bi / 2 <= L) ++bi;
    const int bj = bi + (L - (NT * bi - bi * (bi - 1) / 2));

    // fold 528 max partials (3 loads + shuffle), issued before staging
    float pv = fmaxf(pmax[t], pmax[t + 256]);
    if (t < NBLK - 512) pv = fmaxf(pv, pmax[t + 512]);

    // ---- Stage tiles transposed [dim][idx] ----
    {
        const int r  = t & 63;
        const int c0 = (t >> 6) << 4;   // 0,16,32,48
        const int gi = perm[bi * BT + r];
        const int gj = perm[bj * BT + r];
        const float4* pa = (const float4*)(emb + (size_t)gi * DE + c0);
        const float4* pb = (const float4*)(emb + (size_t)gj * DE + c0);
        float4 a0 = pa[0], a1 = pa[1], a2 = pa[2], a3 = pa[3];
        float4 b0 = pb[0], b1 = pb[1], b2 = pb[2], b3 = pb[3];
        sh.loss.Eit[c0 + 0][r]  = a0.x; sh.loss.Eit[c0 + 1][r]  = a0.y;
        sh.loss.Eit[c0 + 2][r]  = a0.z; sh.loss.Eit[c0 + 3][r]  = a0.w;
        sh.loss.Eit[c0 + 4][r]  = a1.x; sh.loss.Eit[c0 + 5][r]  = a1.y;
        sh.loss.Eit[c0 + 6][r]  = a1.z; sh.loss.Eit[c0 + 7][r]  = a1.w;
        sh.loss.Eit[c0 + 8][r]  = a2.x; sh.loss.Eit[c0 + 9][r]  = a2.y;
        sh.loss.Eit[c0 + 10][r] = a2.z; sh.loss.Eit[c0 + 11][r] = a2.w;
        sh.loss.Eit[c0 + 12][r] = a3.x; sh.loss.Eit[c0 + 13][r] = a3.y;
        sh.loss.Eit[c0 + 14][r] = a3.z; sh.loss.Eit[c0 + 15][r] = a3.w;
        sh.loss.Ejt[c0 + 0][r]  = b0.x; sh.loss.Ejt[c0 + 1][r]  = b0.y;
        sh.loss.Ejt[c0 + 2][r]  = b0.z; sh.loss.Ejt[c0 + 3][r]  = b0.w;
        sh.loss.Ejt[c0 + 4][r]  = b1.x; sh.loss.Ejt[c0 + 5][r]  = b1.y;
        sh.loss.Ejt[c0 + 6][r]  = b1.z; sh.loss.Ejt[c0 + 7][r]  = b1.w;
        sh.loss.Ejt[c0 + 8][r]  = b2.x; sh.loss.Ejt[c0 + 9][r]  = b2.y;
        sh.loss.Ejt[c0 + 10][r] = b2.z; sh.loss.Ejt[c0 + 11][r] = b2.w;
        sh.loss.Ejt[c0 + 12][r] = b3.x; sh.loss.Ejt[c0 + 13][r] = b3.y;
        sh.loss.Ejt[c0 + 14][r] = b3.z; sh.loss.Ejt[c0 + 15][r] = b3.w;
        if (t < BT)          sh.loss.idi[t] = sids[bi * BT + t];
        else if (t < 2 * BT) sh.loss.idj[t - BT] = sids[bj * BT + (t - BT)];
    }
    #pragma unroll
    for (int o = 32; o > 0; o >>= 1)
        pv = fmaxf(pv, __shfl_down(pv, o));
    if (lane == 0) sh.loss.wm[wave] = pv;
    __syncthreads();

    const float inv = 1.0f / fmaxf(fmaxf(sh.loss.wm[0], sh.loss.wm[1]),
                                   fmaxf(sh.loss.wm[2], sh.loss.wm[3]));

    const int i0 = (t >> 4) * 4;
    const int j0 = (t & 15) * 4;

    float acc[4][4];
    #pragma unroll
    for (int s = 0; s < 4; ++s)
        #pragma unroll
        for (int c = 0; c < 4; ++c) acc[s][c] = 0.0f;

    // unroll 2 = proven no-spill regime (full unroll spilled in R2/R3/R4)
    #pragma unroll 2
    for (int k = 0; k < 16; ++k) {
        #pragma unroll
        for (int q = 0; q < 4; ++q) {
            const int d = 4 * k + q;
            const float4 a = *(const float4*)&sh.loss.Eit[d][i0];
            const float4 b = *(const float4*)&sh.loss.Ejt[d][j0];
            acc[0][0] += fabsf(a.x - b.x); acc[0][1] += fabsf(a.x - b.y);
            acc[0][2] += fabsf(a.x - b.z); acc[0][3] += fabsf(a.x - b.w);
            acc[1][0] += fabsf(a.y - b.x); acc[1][1] += fabsf(a.y - b.y);
            acc[1][2] += fabsf(a.y - b.z); acc[1][3] += fabsf(a.y - b.w);
            acc[2][0] += fabsf(a.z - b.x); acc[2][1] += fabsf(a.z - b.y);
            acc[2][2] += fabsf(a.z - b.z); acc[2][3] += fabsf(a.z - b.w);
            acc[3][0] += fabsf(a.w - b.x); acc[3][1] += fabsf(a.w - b.y);
            acc[3][2] += fabsf(a.w - b.z); acc[3][3] += fabsf(a.w - b.w);
        }
    }

    // Epilogue: fused metric gather (sorted ids -> L2-local lines)
    float pp = 0.0f;
    unsigned cnt = 0;
    #pragma unroll
    for (int s = 0; s < 4; ++s) {
        const int ia = sh.loss.idi[i0 + s];
        #pragma unroll
        for (int c = 0; c < 4; ++c) {
            const int ja = sh.loss.idj[j0 + c];
            const int off = ia * VV + ja;
            const float metric = (tree[off] + mapd[off] * inv) * 0.5f;
            if (ia != ja) {
                pp += fabsf(acc[s][c] * (1.0f / (float)DE) - metric);
                cnt += 1u;
            }
        }
    }

    #pragma unroll
    for (int o = 32; o > 0; o >>= 1) {
        pp  += __shfl_down(pp, o);
        cnt += __shfl_down(cnt, o);
    }
    if (lane == 0) { sh.loss.wsum_l[wave] = pp; sh.loss.wcnt_l[wave] = cnt; }
    __syncthreads();
    if (t == 0) {
        const float    w = (bi == bj) ? 1.0f : 2.0f;
        const unsigned u = (bi == bj) ? 1u : 2u;
        psum[L] = (sh.loss.wsum_l[0] + sh.loss.wsum_l[1] +
                   sh.loss.wsum_l[2] + sh.loss.wsum_l[3]) * w;
        pcnt[L] = (sh.loss.wcnt_l[0] + sh.loss.wcnt_l[1] +
                   sh.loss.wcnt_l[2] + sh.loss.wcnt_l[3]) * u;
    }

    grid.sync();

    // ================= Phase 2: block 0 finalizes ================================
    if (L == 0) {
        double   s = (double)psum[t] + (double)psum[t + 256];
        unsigned c = pcnt[t] + pcnt[t + 256];
        if (t < NBLK - 512) { s += (double)psum[t + 512]; c += pcnt[t + 512]; }
        #pragma unroll
        for (int o = 32; o > 0; o >>= 1) {
            s += __shfl_down(s, o);
            c += __shfl_down(c, o);
        }
        if (lane == 0) { sh.fin.sl[wave] = s; sh.fin.cl[wave] = c; }
        __syncthreads();
        if (t == 0) {
            double   S = sh.fin.sl[0] + sh.fin.sl[1] + sh.fin.sl[2] + sh.fin.sl[3];
            unsigned C = sh.fin.cl[0] + sh.fin.cl[1] + sh.fin.cl[2] + sh.fin.cl[3];
            out[0] = (float)(S / (double)C);
        }
    }
}

extern "C" void kernel_launch(void* const* d_in, const int* in_sizes, int n_in,
                              void* d_out, int out_size, void* d_ws, size_t ws_size,
                              hipStream_t stream) {
    const int*   ids  = (const int*)d_in[0];
    const float* emb  = (const float*)d_in[1];
    const float* tree = (const float*)d_in[2];
    const float* mapd = (const float*)d_in[3];
    float* out = (float*)d_out;

    float*    pmax = (float*)d_ws;                       // 528 floats
    float*    psum = (float*)((char*)d_ws + 4096);       // 528 floats
    unsigned* pcnt = (unsigned*)((char*)d_ws + 8192);    // 528 uints
    int*      perm = (int*)((char*)d_ws + 12288);        // 2048 ints
    int*      sids = (int*)((char*)d_ws + 20480);        // 2048 ints

    void* args[] = { (void*)&ids, (void*)&emb, (void*)&tree, (void*)&mapd,
                     (void*)&pmax, (void*)&perm, (void*)&sids,
                     (void*)&psum, (void*)&pcnt, (void*)&out };
    hipLaunchCooperativeKernel((void*)fused_kernel, dim3(NBLK), dim3(256),
                               args, 0, stream);
}

// Round 11
// 110.646 us; speedup vs baseline: 1.9511x; 1.9511x over previous
//
#include <hip/hip_runtime.h>
#include <hip/hip_bf16.h>

#define NL 2048   // languages
#define DE 64     // embedding dim
#define VV 2048   // vocab
#define BT 64     // pair tile (64x64)
#define NT (NL / BT)              // 32 tiles per side
#define NBLK (NT * (NT + 1) / 2)  // 528 triangular tiles
#define STT 68    // [dim][idx] row stride: reads land 2-way max (free)

// ws layout (prep initializes everything that needs init; ws is 0xAA-poisoned每 replay):
// [0:1024)      float pmax[256]
// [1024:9216)   int   perm[2048]
// [9216:17408)  int   sids[2048]
// [17408:19520) float psum[528]
// [19520:21632) uint  pcnt[528]
// [21632:21636) uint  done      (zeroed by prep block 0 every call)

// Blocks 0..255: block-local max over map_dist slice -> pmax[b] (plain store).
// Block 256: counting-sort 2048 ids in LDS.
__global__ __launch_bounds__(1024) void prep_kernel(const int* __restrict__ ids,
                                                    const float4* __restrict__ m4,
                                                    float* __restrict__ pmax,
                                                    int* __restrict__ perm,
                                                    int* __restrict__ sids,
                                                    unsigned* __restrict__ done) {
    const int t = threadIdx.x;
    const int lane = t & 63, wave = t >> 6;
    const int b = blockIdx.x;

    if (b < 256) {
        if (b == 0 && t == 0) *done = 0u;   // re-arm the loss finalize counter
        const float4* p = m4 + (size_t)b * 4096;
        const float4 x0 = p[t], x1 = p[t + 1024], x2 = p[t + 2048], x3 = p[t + 3072];
        float v = fmaxf(fmaxf(fmaxf(x0.x, x0.y), fmaxf(x0.z, x0.w)),
                        fmaxf(fmaxf(x1.x, x1.y), fmaxf(x1.z, x1.w)));
        v = fmaxf(v, fmaxf(fmaxf(x2.x, x2.y), fmaxf(x2.z, x2.w)));
        v = fmaxf(v, fmaxf(fmaxf(x3.x, x3.y), fmaxf(x3.z, x3.w)));
        #pragma unroll
        for (int o = 32; o > 0; o >>= 1)
            v = fmaxf(v, __shfl_down(v, o));
        __shared__ float wl[16];
        if (lane == 0) wl[wave] = v;
        __syncthreads();
        if (t == 0) {
            float m = wl[0];
            #pragma unroll
            for (int i = 1; i < 16; ++i) m = fmaxf(m, wl[i]);
            pmax[b] = m;   // plain store — no init required
        }
    } else {
        __shared__ unsigned hist[VV];
        __shared__ unsigned offs[VV];
        __shared__ unsigned wtot[16];
        __shared__ unsigned wexc[16];
        hist[2 * t] = 0u; hist[2 * t + 1] = 0u;
        __syncthreads();
        const int id0 = ids[2 * t], id1 = ids[2 * t + 1];
        atomicAdd(&hist[id0], 1u);
        atomicAdd(&hist[id1], 1u);
        __syncthreads();
        const unsigned h0 = hist[2 * t], h1 = hist[2 * t + 1];
        const unsigned s = h0 + h1;
        unsigned ps = s;
        #pragma unroll
        for (int o = 1; o < 64; o <<= 1) {
            unsigned u = __shfl_up(ps, o);
            if (lane >= o) ps += u;
        }
        if (lane == 63) wtot[wave] = ps;
        __syncthreads();
        if (wave == 0 && lane < 16) {
            unsigned v = wtot[lane];
            unsigned pv = v;
            #pragma unroll
            for (int o = 1; o < 16; o <<= 1) {
                unsigned u = __shfl_up(pv, o);
                if (lane >= o) pv += u;
            }
            wexc[lane] = pv - v;
        }
        __syncthreads();
        const unsigned ex = wexc[wave] + ps - s;
        offs[2 * t]     = ex;
        offs[2 * t + 1] = ex + h0;
        __syncthreads();
        unsigned p0 = atomicAdd(&offs[id0], 1u);
        perm[p0] = 2 * t;     sids[p0] = id0;
        unsigned p1 = atomicAdd(&offs[id1], 1u);
        perm[p1] = 2 * t + 1; sids[p1] = id1;
    }
}

__global__ __launch_bounds__(256) void loss_kernel(
    const float* __restrict__ emb,
    const float* __restrict__ tree, const float* __restrict__ mapd,
    const int* __restrict__ perm, const int* __restrict__ sids,
    const float* __restrict__ pmax,
    float* __restrict__ psum, unsigned* __restrict__ pcnt,
    unsigned* __restrict__ done, float* __restrict__ out)
{
    const int t = threadIdx.x;

    // Triangular decode (NT=32): L -> (bi, bj), bi <= bj
    const int L = blockIdx.x;
    int bi = (int)((65.0f - sqrtf(4225.0f - 8.0f * (float)L)) * 0.5f);
    if (bi > NT - 1) bi = NT - 1;
    if (bi < 0) bi = 0;
    while (NT * bi - bi * (bi - 1) / 2 > L) --bi;
    while (NT * (bi + 1) - (bi + 1) * bi / 2 <= L) ++bi;
    const int bj = bi + (L - (NT * bi - bi * (bi - 1) / 2));

    // BOTH tiles transposed [dim][idx]: all main-loop b128 reads are 2-way max (free).
    __shared__ __align__(16) float Eit[DE][STT];
    __shared__ __align__(16) float Ejt[DE][STT];
    __shared__ int idi[BT];
    __shared__ int idj[BT];
    __shared__ float wm[4];

    // max partials: independent load issued first
    float pv = pmax[t];

    // ---- Stage: 256 threads, each loads 16 floats/side, transposes into LDS ----
    {
        const int r  = t & 63;
        const int c0 = (t >> 6) << 4;   // 0,16,32,48
        const int gi = perm[bi * BT + r];
        const int gj = perm[bj * BT + r];
        const float4* pa = (const float4*)(emb + (size_t)gi * DE + c0);
        const float4* pb = (const float4*)(emb + (size_t)gj * DE + c0);
        float4 a0 = pa[0], a1 = pa[1], a2 = pa[2], a3 = pa[3];
        float4 b0 = pb[0], b1 = pb[1], b2 = pb[2], b3 = pb[3];
        Eit[c0 + 0][r]  = a0.x; Eit[c0 + 1][r]  = a0.y; Eit[c0 + 2][r]  = a0.z; Eit[c0 + 3][r]  = a0.w;
        Eit[c0 + 4][r]  = a1.x; Eit[c0 + 5][r]  = a1.y; Eit[c0 + 6][r]  = a1.z; Eit[c0 + 7][r]  = a1.w;
        Eit[c0 + 8][r]  = a2.x; Eit[c0 + 9][r]  = a2.y; Eit[c0 + 10][r] = a2.z; Eit[c0 + 11][r] = a2.w;
        Eit[c0 + 12][r] = a3.x; Eit[c0 + 13][r] = a3.y; Eit[c0 + 14][r] = a3.z; Eit[c0 + 15][r] = a3.w;
        Ejt[c0 + 0][r]  = b0.x; Ejt[c0 + 1][r]  = b0.y; Ejt[c0 + 2][r]  = b0.z; Ejt[c0 + 3][r]  = b0.w;
        Ejt[c0 + 4][r]  = b1.x; Ejt[c0 + 5][r]  = b1.y; Ejt[c0 + 6][r]  = b1.z; Ejt[c0 + 7][r]  = b1.w;
        Ejt[c0 + 8][r]  = b2.x; Ejt[c0 + 9][r]  = b2.y; Ejt[c0 + 10][r] = b2.z; Ejt[c0 + 11][r] = b2.w;
        Ejt[c0 + 12][r] = b3.x; Ejt[c0 + 13][r] = b3.y; Ejt[c0 + 14][r] = b3.z; Ejt[c0 + 15][r] = b3.w;
        if (t < BT)          idi[t] = sids[bi * BT + t];
        else if (t < 2 * BT) idj[t - BT] = sids[bj * BT + (t - BT)];
    }
    #pragma unroll
    for (int o = 32; o > 0; o >>= 1)
        pv = fmaxf(pv, __shfl_down(pv, o));
    if ((t & 63) == 0) wm[t >> 6] = pv;
    __syncthreads();

    const float inv = 1.0f / fmaxf(fmaxf(wm[0], wm[1]), fmaxf(wm[2], wm[3]));

    const int i0 = (t >> 4) * 4;   // 16 groups x 4 rows
    const int j0 = (t & 15) * 4;   // 16 groups x 4 cols

    float acc[4][4];
    #pragma unroll
    for (int s = 0; s < 4; ++s)
        #pragma unroll
        for (int c = 0; c < 4; ++c) acc[s][c] = 0.0f;

    // 4x4 tile, unroll 2 = proven no-spill regime (full unroll spilled in R2/R3/R4)
    #pragma unroll 2
    for (int k = 0; k < 16; ++k) {
        #pragma unroll
        for (int q = 0; q < 4; ++q) {
            const int d = 4 * k + q;
            const float4 a = *(const float4*)&Eit[d][i0];
            const float4 b = *(const float4*)&Ejt[d][j0];
            acc[0][0] += fabsf(a.x - b.x); acc[0][1] += fabsf(a.x - b.y);
            acc[0][2] += fabsf(a.x - b.z); acc[0][3] += fabsf(a.x - b.w);
            acc[1][0] += fabsf(a.y - b.x); acc[1][1] += fabsf(a.y - b.y);
            acc[1][2] += fabsf(a.y - b.z); acc[1][3] += fabsf(a.y - b.w);
            acc[2][0] += fabsf(a.z - b.x); acc[2][1] += fabsf(a.z - b.y);
            acc[2][2] += fabsf(a.z - b.z); acc[2][3] += fabsf(a.z - b.w);
            acc[3][0] += fabsf(a.w - b.x); acc[3][1] += fabsf(a.w - b.y);
            acc[3][2] += fabsf(a.w - b.z); acc[3][3] += fabsf(a.w - b.w);
        }
    }

    // ---- Epilogue: fused metric gather (sorted ids -> L2-local lines) ----
    float pp = 0.0f;
    unsigned cnt = 0;
    #pragma unroll
    for (int s = 0; s < 4; ++s) {
        const int ia = idi[i0 + s];
        #pragma unroll
        for (int c = 0; c < 4; ++c) {
            const int ja = idj[j0 + c];
            const int off = ia * VV + ja;
            const float metric = (tree[off] + mapd[off] * inv) * 0.5f;
            if (ia != ja) {
                pp += fabsf(acc[s][c] * (1.0f / (float)DE) - metric);
                cnt += 1u;
            }
        }
    }

    #pragma unroll
    for (int o = 32; o > 0; o >>= 1) {
        pp  += __shfl_down(pp, o);
        cnt += __shfl_down(cnt, o);
    }
    __shared__ float    wsum_l[4];
    __shared__ unsigned wcnt_l[4];
    if ((t & 63) == 0) { wsum_l[t >> 6] = pp; wcnt_l[t >> 6] = cnt; }
    __syncthreads();

    __shared__ unsigned amlast;
    if (t == 0) {
        const float    w = (bi == bj) ? 1.0f : 2.0f;
        const unsigned u = (bi == bj) ? 1u : 2u;
        psum[L] = (wsum_l[0] + wsum_l[1] + wsum_l[2] + wsum_l[3]) * w;  // plain store, distinct word
        pcnt[L] = (wcnt_l[0] + wcnt_l[1] + wcnt_l[2] + wcnt_l[3]) * u;
        __threadfence();                          // release: make partials visible device-wide
        amlast = (atomicAdd(done, 1u) == (unsigned)NBLK - 1u);  // ONE atomic per block
    }
    __syncthreads();

    // Last block to finish reduces all 528 partials (coherent atomic reads, distinct addrs).
    if (amlast) {
        __threadfence();
        const int lane = t & 63, wave = t >> 6;
        double   s = 0.0;
        unsigned c = 0;
        if (t < NBLK) {
            s = (double)atomicAdd(&psum[t], 0.0f);
            c = atomicAdd(&pcnt[t], 0u);
        }
        if (t + 256 < NBLK) {
            s += (double)atomicAdd(&psum[t + 256], 0.0f);
            c += atomicAdd(&pcnt[t + 256], 0u);
        }
        if (t + 512 < NBLK) {
            s += (double)atomicAdd(&psum[t + 512], 0.0f);
            c += atomicAdd(&pcnt[t + 512], 0u);
        }
        #pragma unroll
        for (int o = 32; o > 0; o >>= 1) {
            s += __shfl_down(s, o);
            c += __shfl_down(c, o);
        }
        __shared__ double   sl[4];
        __shared__ unsigned cl[4];
        if (lane == 0) { sl[wave] = s; cl[wave] = c; }
        __syncthreads();
        if (t == 0) {
            const double   S = sl[0] + sl[1] + sl[2] + sl[3];
            const unsigned C = cl[0] + cl[1] + cl[2] + cl[3];
            out[0] = (float)(S / (double)C);
        }
    }
}

extern "C" void kernel_launch(void* const* d_in, const int* in_sizes, int n_in,
                              void* d_out, int out_size, void* d_ws, size_t ws_size,
                              hipStream_t stream) {
    const int*   ids  = (const int*)d_in[0];
    const float* emb  = (const float*)d_in[1];
    const float* tree = (const float*)d_in[2];
    const float* mapd = (const float*)d_in[3];
    float* out = (float*)d_out;

    float*    pmax = (float*)d_ws;                        // 256 floats
    int*      perm = (int*)((char*)d_ws + 1024);          // 2048 ints
    int*      sids = (int*)((char*)d_ws + 9216);          // 2048 ints
    float*    psum = (float*)((char*)d_ws + 17408);       // 528 floats
    unsigned* pcnt = (unsigned*)((char*)d_ws + 19520);    // 528 uints
    unsigned* done = (unsigned*)((char*)d_ws + 21632);    // 1 uint

    prep_kernel<<<257, 1024, 0, stream>>>(ids, (const float4*)mapd, pmax, perm, sids, done);

    loss_kernel<<<NBLK, 256, 0, stream>>>(emb, tree, mapd, perm, sids, pmax,
                                          psum, pcnt, done, out);
}

// Round 12
// 103.150 us; speedup vs baseline: 2.0929x; 1.0727x over previous
//
#include <hip/hip_runtime.h>
#include <hip/hip_bf16.h>

#define NL 2048   // languages
#define DE 64     // embedding dim
#define VV 2048   // vocab
#define BT 64     // pair tile (64x64)
#define NT (NL / BT)              // 32 tiles per side
#define NBLK (NT * (NT + 1) / 2)  // 528 triangular tiles
#define STT 68    // [dim][idx] row stride: reads land 2-way max (free)

// ws layout (no memset needed — every word is written before read):
// [0:1024)      float pmax[256]
// [1024:9216)   int   perm[2048]
// [9216:17408)  int   sids[2048]
// [17408:19520) float psum[528]
// [19520:21632) uint  pcnt[528]

// Blocks 0..255: block-local max over map_dist slice -> pmax[b] (plain store).
// Block 256: counting-sort 2048 ids in LDS.
__global__ __launch_bounds__(1024) void prep_kernel(const int* __restrict__ ids,
                                                    const float4* __restrict__ m4,
                                                    float* __restrict__ pmax,
                                                    int* __restrict__ perm,
                                                    int* __restrict__ sids) {
    const int t = threadIdx.x;
    const int lane = t & 63, wave = t >> 6;
    const int b = blockIdx.x;

    if (b < 256) {
        const float4* p = m4 + (size_t)b * 4096;
        const float4 x0 = p[t], x1 = p[t + 1024], x2 = p[t + 2048], x3 = p[t + 3072];
        float v = fmaxf(fmaxf(fmaxf(x0.x, x0.y), fmaxf(x0.z, x0.w)),
                        fmaxf(fmaxf(x1.x, x1.y), fmaxf(x1.z, x1.w)));
        v = fmaxf(v, fmaxf(fmaxf(x2.x, x2.y), fmaxf(x2.z, x2.w)));
        v = fmaxf(v, fmaxf(fmaxf(x3.x, x3.y), fmaxf(x3.z, x3.w)));
        #pragma unroll
        for (int o = 32; o > 0; o >>= 1)
            v = fmaxf(v, __shfl_down(v, o));
        __shared__ float wl[16];
        if (lane == 0) wl[wave] = v;
        __syncthreads();
        if (t == 0) {
            float m = wl[0];
            #pragma unroll
            for (int i = 1; i < 16; ++i) m = fmaxf(m, wl[i]);
            pmax[b] = m;
        }
    } else {
        __shared__ unsigned hist[VV];
        __shared__ unsigned offs[VV];
        __shared__ unsigned wtot[16];
        __shared__ unsigned wexc[16];
        hist[2 * t] = 0u; hist[2 * t + 1] = 0u;
        __syncthreads();
        const int id0 = ids[2 * t], id1 = ids[2 * t + 1];
        atomicAdd(&hist[id0], 1u);
        atomicAdd(&hist[id1], 1u);
        __syncthreads();
        const unsigned h0 = hist[2 * t], h1 = hist[2 * t + 1];
        const unsigned s = h0 + h1;
        unsigned ps = s;
        #pragma unroll
        for (int o = 1; o < 64; o <<= 1) {
            unsigned u = __shfl_up(ps, o);
            if (lane >= o) ps += u;
        }
        if (lane == 63) wtot[wave] = ps;
        __syncthreads();
        if (wave == 0 && lane < 16) {
            unsigned v = wtot[lane];
            unsigned pv = v;
            #pragma unroll
            for (int o = 1; o < 16; o <<= 1) {
                unsigned u = __shfl_up(pv, o);
                if (lane >= o) pv += u;
            }
            wexc[lane] = pv - v;
        }
        __syncthreads();
        const unsigned ex = wexc[wave] + ps - s;
        offs[2 * t]     = ex;
        offs[2 * t + 1] = ex + h0;
        __syncthreads();
        unsigned p0 = atomicAdd(&offs[id0], 1u);
        perm[p0] = 2 * t;     sids[p0] = id0;
        unsigned p1 = atomicAdd(&offs[id1], 1u);
        perm[p1] = 2 * t + 1; sids[p1] = id1;
    }
}

__global__ __launch_bounds__(256) void loss_kernel(
    const float* __restrict__ emb,
    const float* __restrict__ tree, const float* __restrict__ mapd,
    const int* __restrict__ perm, const int* __restrict__ sids,
    const float* __restrict__ pmax,
    float* __restrict__ psum, unsigned* __restrict__ pcnt)
{
    const int t = threadIdx.x;

    // Triangular decode (NT=32): L -> (bi, bj), bi <= bj
    const int L = blockIdx.x;
    int bi = (int)((65.0f - sqrtf(4225.0f - 8.0f * (float)L)) * 0.5f);
    if (bi > NT - 1) bi = NT - 1;
    if (bi < 0) bi = 0;
    while (NT * bi - bi * (bi - 1) / 2 > L) --bi;
    while (NT * (bi + 1) - (bi + 1) * bi / 2 <= L) ++bi;
    const int bj = bi + (L - (NT * bi - bi * (bi - 1) / 2));

    // BOTH tiles transposed [dim][idx]: all main-loop b128 reads are 2-way max (free).
    __shared__ __align__(16) float Eit[DE][STT];
    __shared__ __align__(16) float Ejt[DE][STT];
    __shared__ int idi[BT];
    __shared__ int idj[BT];
    __shared__ float wm[4];

    // max partials: independent load issued first
    float pv = pmax[t];

    // ---- Stage: 256 threads, each loads 16 floats/side, transposes into LDS ----
    {
        const int r  = t & 63;
        const int c0 = (t >> 6) << 4;   // 0,16,32,48
        const int gi = perm[bi * BT + r];
        const int gj = perm[bj * BT + r];
        const float4* pa = (const float4*)(emb + (size_t)gi * DE + c0);
        const float4* pb = (const float4*)(emb + (size_t)gj * DE + c0);
        float4 a0 = pa[0], a1 = pa[1], a2 = pa[2], a3 = pa[3];
        float4 b0 = pb[0], b1 = pb[1], b2 = pb[2], b3 = pb[3];
        Eit[c0 + 0][r]  = a0.x; Eit[c0 + 1][r]  = a0.y; Eit[c0 + 2][r]  = a0.z; Eit[c0 + 3][r]  = a0.w;
        Eit[c0 + 4][r]  = a1.x; Eit[c0 + 5][r]  = a1.y; Eit[c0 + 6][r]  = a1.z; Eit[c0 + 7][r]  = a1.w;
        Eit[c0 + 8][r]  = a2.x; Eit[c0 + 9][r]  = a2.y; Eit[c0 + 10][r] = a2.z; Eit[c0 + 11][r] = a2.w;
        Eit[c0 + 12][r] = a3.x; Eit[c0 + 13][r] = a3.y; Eit[c0 + 14][r] = a3.z; Eit[c0 + 15][r] = a3.w;
        Ejt[c0 + 0][r]  = b0.x; Ejt[c0 + 1][r]  = b0.y; Ejt[c0 + 2][r]  = b0.z; Ejt[c0 + 3][r]  = b0.w;
        Ejt[c0 + 4][r]  = b1.x; Ejt[c0 + 5][r]  = b1.y; Ejt[c0 + 6][r]  = b1.z; Ejt[c0 + 7][r]  = b1.w;
        Ejt[c0 + 8][r]  = b2.x; Ejt[c0 + 9][r]  = b2.y; Ejt[c0 + 10][r] = b2.z; Ejt[c0 + 11][r] = b2.w;
        Ejt[c0 + 12][r] = b3.x; Ejt[c0 + 13][r] = b3.y; Ejt[c0 + 14][r] = b3.z; Ejt[c0 + 15][r] = b3.w;
        if (t < BT)          idi[t] = sids[bi * BT + t];
        else if (t < 2 * BT) idj[t - BT] = sids[bj * BT + (t - BT)];
    }
    #pragma unroll
    for (int o = 32; o > 0; o >>= 1)
        pv = fmaxf(pv, __shfl_down(pv, o));
    if ((t & 63) == 0) wm[t >> 6] = pv;
    __syncthreads();

    const float inv = 1.0f / fmaxf(fmaxf(wm[0], wm[1]), fmaxf(wm[2], wm[3]));

    const int i0 = (t >> 4) * 4;   // 16 groups x 4 rows
    const int j0 = (t & 15) * 4;   // 16 groups x 4 cols

    // ---- Issue the 32 scattered metric gathers EARLY: their ~300-900 cyc
    // latency hides under the ~6000-cyc k-loop. Raw values kept in regs;
    // combined AFTER the loop (combining here would wait on the loads).
    int ia[4], ja[4];
    #pragma unroll
    for (int s = 0; s < 4; ++s) { ia[s] = idi[i0 + s]; ja[s] = idj[j0 + s]; }
    float tg[4][4], mg[4][4];
    #pragma unroll
    for (int s = 0; s < 4; ++s)
        #pragma unroll
        for (int c = 0; c < 4; ++c) {
            const int off = ia[s] * VV + ja[c];   // sorted ids -> L1/L2-local lines
            tg[s][c] = tree[off];
            mg[s][c] = mapd[off];
        }

    float acc[4][4];
    #pragma unroll
    for (int s = 0; s < 4; ++s)
        #pragma unroll
        for (int c = 0; c < 4; ++c) acc[s][c] = 0.0f;

    // 4x4 tile, unroll 2 = proven no-spill regime (full unroll spilled in R2/R3/R4)
    #pragma unroll 2
    for (int k = 0; k < 16; ++k) {
        #pragma unroll
        for (int q = 0; q < 4; ++q) {
            const int d = 4 * k + q;
            const float4 a = *(const float4*)&Eit[d][i0];
            const float4 b = *(const float4*)&Ejt[d][j0];
            acc[0][0] += fabsf(a.x - b.x); acc[0][1] += fabsf(a.x - b.y);
            acc[0][2] += fabsf(a.x - b.z); acc[0][3] += fabsf(a.x - b.w);
            acc[1][0] += fabsf(a.y - b.x); acc[1][1] += fabsf(a.y - b.y);
            acc[1][2] += fabsf(a.y - b.z); acc[1][3] += fabsf(a.y - b.w);
            acc[2][0] += fabsf(a.z - b.x); acc[2][1] += fabsf(a.z - b.y);
            acc[2][2] += fabsf(a.z - b.z); acc[2][3] += fabsf(a.z - b.w);
            acc[3][0] += fabsf(a.w - b.x); acc[3][1] += fabsf(a.w - b.y);
            acc[3][2] += fabsf(a.w - b.z); acc[3][3] += fabsf(a.w - b.w);
        }
    }

    // ---- Epilogue: combine pre-gathered metric (no memory waits here) ----
    float pp = 0.0f;
    unsigned cnt = 0;
    #pragma unroll
    for (int s = 0; s < 4; ++s)
        #pragma unroll
        for (int c = 0; c < 4; ++c) {
            const float metric = (tg[s][c] + mg[s][c] * inv) * 0.5f;
            if (ia[s] != ja[c]) {
                pp += fabsf(acc[s][c] * (1.0f / (float)DE) - metric);
                cnt += 1u;
            }
        }

    #pragma unroll
    for (int o = 32; o > 0; o >>= 1) {
        pp  += __shfl_down(pp, o);
        cnt += __shfl_down(cnt, o);
    }
    __shared__ float    wsum_l[4];
    __shared__ unsigned wcnt_l[4];
    if ((t & 63) == 0) { wsum_l[t >> 6] = pp; wcnt_l[t >> 6] = cnt; }
    __syncthreads();
    if (t == 0) {
        const float    w = (bi == bj) ? 1.0f : 2.0f;
        const unsigned u = (bi == bj) ? 1u : 2u;
        psum[L] = (wsum_l[0] + wsum_l[1] + wsum_l[2] + wsum_l[3]) * w;  // plain stores, no atomics
        pcnt[L] = (wcnt_l[0] + wcnt_l[1] + wcnt_l[2] + wcnt_l[3]) * u;
    }
}

__global__ __launch_bounds__(1024) void finalize_kernel(const float* __restrict__ psum,
                                                        const unsigned* __restrict__ pcnt,
                                                        float* __restrict__ out) {
    const int t = threadIdx.x;
    const int lane = t & 63, wave = t >> 6;
    double s = 0.0;
    unsigned c = 0;
    if (t < NBLK) { s = (double)psum[t]; c = pcnt[t]; }
    #pragma unroll
    for (int o = 32; o > 0; o >>= 1) {
        s += __shfl_down(s, o);
        c += __shfl_down(c, o);
    }
    __shared__ double   sl[16];
    __shared__ unsigned cl[16];
    if (lane == 0) { sl[wave] = s; cl[wave] = c; }
    __syncthreads();
    if (t == 0) {
        double   S = sl[0];
        unsigned C = cl[0];
        #pragma unroll
        for (int i = 1; i < 16; ++i) { S += sl[i]; C += cl[i]; }
        out[0] = (float)(S / (double)C);
    }
}

extern "C" void kernel_launch(void* const* d_in, const int* in_sizes, int n_in,
                              void* d_out, int out_size, void* d_ws, size_t ws_size,
                              hipStream_t stream) {
    const int*   ids  = (const int*)d_in[0];
    const float* emb  = (const float*)d_in[1];
    const float* tree = (const float*)d_in[2];
    const float* mapd = (const float*)d_in[3];
    float* out = (float*)d_out;

    float*    pmax = (float*)d_ws;                        // 256 floats
    int*      perm = (int*)((char*)d_ws + 1024);          // 2048 ints
    int*      sids = (int*)((char*)d_ws + 9216);          // 2048 ints
    float*    psum = (float*)((char*)d_ws + 17408);       // 528 floats
    unsigned* pcnt = (unsigned*)((char*)d_ws + 19520);    // 528 uints

    prep_kernel<<<257, 1024, 0, stream>>>(ids, (const float4*)mapd, pmax, perm, sids);

    loss_kernel<<<NBLK, 256, 0, stream>>>(emb, tree, mapd, perm, sids, pmax, psum, pcnt);

    finalize_kernel<<<1, 1024, 0, stream>>>(psum, pcnt, out);
}

// Round 13
// 100.489 us; speedup vs baseline: 2.1483x; 1.0265x over previous
//
#include <hip/hip_runtime.h>
#include <hip/hip_bf16.h>

#define NL 2048   // languages
#define DE 64     // embedding dim
#define VV 2048   // vocab
#define BI 64     // i-tile rows
#define BJ 32     // j-tile cols
#define NTI (NL / BI)             // 32 i-tiles
#define NTJ (NL / BJ)             // 64 j-tiles
#define NBLK 1056                 // sum_{bi=0}^{31} (64 - 2*bi)
#define STI 68    // Eit [dim][i] stride
#define STJ 36    // Ejt [dim][j] stride

// ws layout (no memset needed — every word is written before read):
// [0:1024)      float pmax[256]
// [1024:9216)   int   perm[2048]
// [9216:17408)  int   sids[2048]
// [17408:21632) float psum[1056]
// [21632:25856) uint  pcnt[1056]

// Blocks 0..255: block-local max over map_dist slice -> pmax[b] (plain store).
// Block 256: counting-sort 2048 ids in LDS.
__global__ __launch_bounds__(1024) void prep_kernel(const int* __restrict__ ids,
                                                    const float4* __restrict__ m4,
                                                    float* __restrict__ pmax,
                                                    int* __restrict__ perm,
                                                    int* __restrict__ sids) {
    const int t = threadIdx.x;
    const int lane = t & 63, wave = t >> 6;
    const int b = blockIdx.x;

    if (b < 256) {
        const float4* p = m4 + (size_t)b * 4096;
        const float4 x0 = p[t], x1 = p[t + 1024], x2 = p[t + 2048], x3 = p[t + 3072];
        float v = fmaxf(fmaxf(fmaxf(x0.x, x0.y), fmaxf(x0.z, x0.w)),
                        fmaxf(fmaxf(x1.x, x1.y), fmaxf(x1.z, x1.w)));
        v = fmaxf(v, fmaxf(fmaxf(x2.x, x2.y), fmaxf(x2.z, x2.w)));
        v = fmaxf(v, fmaxf(fmaxf(x3.x, x3.y), fmaxf(x3.z, x3.w)));
        #pragma unroll
        for (int o = 32; o > 0; o >>= 1)
            v = fmaxf(v, __shfl_down(v, o));
        __shared__ float wl[16];
        if (lane == 0) wl[wave] = v;
        __syncthreads();
        if (t == 0) {
            float m = wl[0];
            #pragma unroll
            for (int i = 1; i < 16; ++i) m = fmaxf(m, wl[i]);
            pmax[b] = m;
        }
    } else {
        __shared__ unsigned hist[VV];
        __shared__ unsigned offs[VV];
        __shared__ unsigned wtot[16];
        __shared__ unsigned wexc[16];
        hist[2 * t] = 0u; hist[2 * t + 1] = 0u;
        __syncthreads();
        const int id0 = ids[2 * t], id1 = ids[2 * t + 1];
        atomicAdd(&hist[id0], 1u);
        atomicAdd(&hist[id1], 1u);
        __syncthreads();
        const unsigned h0 = hist[2 * t], h1 = hist[2 * t + 1];
        const unsigned s = h0 + h1;
        unsigned ps = s;
        #pragma unroll
        for (int o = 1; o < 64; o <<= 1) {
            unsigned u = __shfl_up(ps, o);
            if (lane >= o) ps += u;
        }
        if (lane == 63) wtot[wave] = ps;
        __syncthreads();
        if (wave == 0 && lane < 16) {
            unsigned v = wtot[lane];
            unsigned pv = v;
            #pragma unroll
            for (int o = 1; o < 16; o <<= 1) {
                unsigned u = __shfl_up(pv, o);
                if (lane >= o) pv += u;
            }
            wexc[lane] = pv - v;
        }
        __syncthreads();
        const unsigned ex = wexc[wave] + ps - s;
        offs[2 * t]     = ex;
        offs[2 * t + 1] = ex + h0;
        __syncthreads();
        unsigned p0 = atomicAdd(&offs[id0], 1u);
        perm[p0] = 2 * t;     sids[p0] = id0;
        unsigned p1 = atomicAdd(&offs[id1], 1u);
        perm[p1] = 2 * t + 1; sids[p1] = id1;
    }
}

__global__ __launch_bounds__(256) void loss_kernel(
    const float* __restrict__ emb,
    const float* __restrict__ tree, const float* __restrict__ mapd,
    const int* __restrict__ perm, const int* __restrict__ sids,
    const float* __restrict__ pmax,
    float* __restrict__ psum, unsigned* __restrict__ pcnt)
{
    const int t = threadIdx.x;

    // Rect-tile decode: L -> (bi, bj), bj in [2*bi, 64). cum(bi) = 65*bi - bi^2.
    const int L = blockIdx.x;
    int bi = (int)((65.0f - sqrtf(4225.0f - 4.0f * (float)L)) * 0.5f);
    if (bi > NTI - 1) bi = NTI - 1;
    if (bi < 0) bi = 0;
    while (65 * bi - bi * bi > L) --bi;
    while (65 * (bi + 1) - (bi + 1) * (bi + 1) <= L) ++bi;
    const int bj = 2 * bi + (L - (65 * bi - bi * bi));

    // Tiles transposed [dim][idx]; all k-loop reads broadcast-heavy & conflict-free.
    __shared__ __align__(16) float Eit[DE][STI];
    __shared__ __align__(16) float Ejt[DE][STJ];
    __shared__ int idi[BI];
    __shared__ int idj[BJ];
    __shared__ float wm[4];

    // max partials: independent load issued first
    float pv = pmax[t];

    // ---- Stage: Eit 64 rows (4 f4/thread), Ejt 32 rows (2 f4/thread) ----
    {
        const int r  = t & 63;
        const int c0 = (t >> 6) << 4;   // 0,16,32,48
        const int gi = perm[bi * BI + r];
        const float4* pa = (const float4*)(emb + (size_t)gi * DE + c0);
        float4 a0 = pa[0], a1 = pa[1], a2 = pa[2], a3 = pa[3];
        Eit[c0 + 0][r]  = a0.x; Eit[c0 + 1][r]  = a0.y; Eit[c0 + 2][r]  = a0.z; Eit[c0 + 3][r]  = a0.w;
        Eit[c0 + 4][r]  = a1.x; Eit[c0 + 5][r]  = a1.y; Eit[c0 + 6][r]  = a1.z; Eit[c0 + 7][r]  = a1.w;
        Eit[c0 + 8][r]  = a2.x; Eit[c0 + 9][r]  = a2.y; Eit[c0 + 10][r] = a2.z; Eit[c0 + 11][r] = a2.w;
        Eit[c0 + 12][r] = a3.x; Eit[c0 + 13][r] = a3.y; Eit[c0 + 14][r] = a3.z; Eit[c0 + 15][r] = a3.w;

        const int rj  = t & 31;
        const int cj0 = (t >> 5) << 3;  // 0,8,...,56
        const int gj = perm[bj * BJ + rj];
        const float4* pb = (const float4*)(emb + (size_t)gj * DE + cj0);
        float4 b0 = pb[0], b1 = pb[1];
        Ejt[cj0 + 0][rj] = b0.x; Ejt[cj0 + 1][rj] = b0.y; Ejt[cj0 + 2][rj] = b0.z; Ejt[cj0 + 3][rj] = b0.w;
        Ejt[cj0 + 4][rj] = b1.x; Ejt[cj0 + 5][rj] = b1.y; Ejt[cj0 + 6][rj] = b1.z; Ejt[cj0 + 7][rj] = b1.w;

        if (t < BI)            idi[t] = sids[bi * BI + t];
        else if (t < BI + BJ)  idj[t - BI] = sids[bj * BJ + (t - BI)];
    }
    #pragma unroll
    for (int o = 32; o > 0; o >>= 1)
        pv = fmaxf(pv, __shfl_down(pv, o));
    if ((t & 63) == 0) wm[t >> 6] = pv;
    __syncthreads();

    const float inv = 1.0f / fmaxf(fmaxf(wm[0], wm[1]), fmaxf(wm[2], wm[3]));

    const int i0 = (t >> 4) * 4;   // 16 groups x 4 rows
    const int j0 = (t & 15) * 2;   // 16 groups x 2 cols

    // ---- Hoisted metric gathers (8 pairs): hide under the k-loop ----
    int ia[4], ja[2];
    #pragma unroll
    for (int s = 0; s < 4; ++s) ia[s] = idi[i0 + s];
    #pragma unroll
    for (int c = 0; c < 2; ++c) ja[c] = idj[j0 + c];
    float tg[4][2], mg[4][2];
    #pragma unroll
    for (int s = 0; s < 4; ++s)
        #pragma unroll
        for (int c = 0; c < 2; ++c) {
            const int off = ia[s] * VV + ja[c];
            tg[s][c] = tree[off];
            mg[s][c] = mapd[off];
        }

    float acc[4][2];
    #pragma unroll
    for (int s = 0; s < 4; ++s) { acc[s][0] = 0.0f; acc[s][1] = 0.0f; }

    // unroll 2 = proven no-spill regime
    #pragma unroll 2
    for (int k = 0; k < 16; ++k) {
        #pragma unroll
        for (int q = 0; q < 4; ++q) {
            const int d = 4 * k + q;
            const float4 a = *(const float4*)&Eit[d][i0];
            const float2 b = *(const float2*)&Ejt[d][j0];
            acc[0][0] += fabsf(a.x - b.x); acc[0][1] += fabsf(a.x - b.y);
            acc[1][0] += fabsf(a.y - b.x); acc[1][1] += fabsf(a.y - b.y);
            acc[2][0] += fabsf(a.z - b.x); acc[2][1] += fabsf(a.z - b.y);
            acc[3][0] += fabsf(a.w - b.x); acc[3][1] += fabsf(a.w - b.y);
        }
    }

    // ---- Epilogue: per-pair dedup (pos_i < pos_j -> weight 2; ids mask) ----
    float pp = 0.0f;
    unsigned cnt = 0;
    #pragma unroll
    for (int s = 0; s < 4; ++s) {
        const int posi = bi * BI + i0 + s;
        #pragma unroll
        for (int c = 0; c < 2; ++c) {
            const int posj = bj * BJ + j0 + c;
            if (posi < posj && ia[s] != ja[c]) {
                const float metric = (tg[s][c] + mg[s][c] * inv) * 0.5f;
                pp += 2.0f * fabsf(acc[s][c] * (1.0f / (float)DE) - metric);
                cnt += 2u;
            }
        }
    }

    #pragma unroll
    for (int o = 32; o > 0; o >>= 1) {
        pp  += __shfl_down(pp, o);
        cnt += __shfl_down(cnt, o);
    }
    __shared__ float    wsum_l[4];
    __shared__ unsigned wcnt_l[4];
    if ((t & 63) == 0) { wsum_l[t >> 6] = pp; wcnt_l[t >> 6] = cnt; }
    __syncthreads();
    if (t == 0) {
        psum[L] = wsum_l[0] + wsum_l[1] + wsum_l[2] + wsum_l[3];  // plain stores, no atomics
        pcnt[L] = wcnt_l[0] + wcnt_l[1] + wcnt_l[2] + wcnt_l[3];
    }
}

__global__ __launch_bounds__(1024) void finalize_kernel(const float* __restrict__ psum,
                                                        const unsigned* __restrict__ pcnt,
                                                        float* __restrict__ out) {
    const int t = threadIdx.x;
    const int lane = t & 63, wave = t >> 6;
    double s = 0.0;
    unsigned c = 0;
    for (int i = t; i < NBLK; i += 1024) { s += (double)psum[i]; c += pcnt[i]; }
    #pragma unroll
    for (int o = 32; o > 0; o >>= 1) {
        s += __shfl_down(s, o);
        c += __shfl_down(c, o);
    }
    __shared__ double   sl[16];
    __shared__ unsigned cl[16];
    if (lane == 0) { sl[wave] = s; cl[wave] = c; }
    __syncthreads();
    if (t == 0) {
        double   S = sl[0];
        unsigned C = cl[0];
        #pragma unroll
        for (int i = 1; i < 16; ++i) { S += sl[i]; C += cl[i]; }
        out[0] = (float)(S / (double)C);
    }
}

extern "C" void kernel_launch(void* const* d_in, const int* in_sizes, int n_in,
                              void* d_out, int out_size, void* d_ws, size_t ws_size,
                              hipStream_t stream) {
    const int*   ids  = (const int*)d_in[0];
    const float* emb  = (const float*)d_in[1];
    const float* tree = (const float*)d_in[2];
    const float* mapd = (const float*)d_in[3];
    float* out = (float*)d_out;

    float*    pmax = (float*)d_ws;                        // 256 floats
    int*      perm = (int*)((char*)d_ws + 1024);          // 2048 ints
    int*      sids = (int*)((char*)d_ws + 9216);          // 2048 ints
    float*    psum = (float*)((char*)d_ws + 17408);       // 1056 floats
    unsigned* pcnt = (unsigned*)((char*)d_ws + 21632);    // 1056 uints

    prep_kernel<<<257, 1024, 0, stream>>>(ids, (const float4*)mapd, pmax, perm, sids);

    loss_kernel<<<NBLK, 256, 0, stream>>>(emb, tree, mapd, perm, sids, pmax, psum, pcnt);

    finalize_kernel<<<1, 1024, 0, stream>>>(psum, pcnt, out);
}